// Round 7
// baseline (144.010 us; speedup 1.0000x reference)
//
#include <hip/hip_runtime.h>

// out[b,f,d] = x[b,f] * W[f,d] + b[f,d]   (B=16384, F=64, D=192, fp32)
//
// Round-7: round-6 inner loop (register W/b + LDS-staged x + NT stores),
// geometry cleaned up:
//  - 1536 blocks (6/CU, single residency round, no tail), 128 batches/block
//    staged in two 64-row LDS halves.
//  - XCD-swizzled block id: the 12 column-blocks sharing one x-chunk all
//    land on the same XCD (ids congruent mod 8) -> x fetched once (4 MB).

typedef float floatx4 __attribute__((ext_vector_type(4)));

__global__ __launch_bounds__(256) void ftemb_kernel(
    const float*   __restrict__ x,    // [B*64]
    const floatx4* __restrict__ W,    // [3072] = 64 feats x 48
    const floatx4* __restrict__ Bb,   // [3072]
    floatx4*       __restrict__ out)  // [B*3072]
{
    __shared__ floatx4 xs_lds[1024];               // 16 KB

    // XCD-aware decode: blocks with the same `by` share ids mod 8 -> same XCD L2.
    const int g    = blockIdx.x;                   // 0..1535
    const int xcd  = g & 7;
    const int slot = g >> 3;                       // 0..191
    const int by   = xcd * 16 + slot / 12;         // 0..127 (128-batch chunks)
    const int bx   = slot % 12;                    // 0..11  (256-column chunks)

    const int tid = threadIdx.x;
    const int j   = bx * 256 + tid;                // 0..3071 = f*48 + c
    const int f   = j / 48;

    const floatx4 w  = W[j];                       // loop-invariant registers
    const floatx4 bb = Bb[j];

    const int b0 = by * 128;

    for (int h = 0; h < 2; ++h) {
        const int bh = b0 + h * 64;
        const floatx4* xsrc = (const floatx4*)(x + (size_t)bh * 64);
        __syncthreads();                           // LDS reuse guard (h=1)
        #pragma unroll
        for (int t = 0; t < 4; ++t)
            xs_lds[t * 256 + tid] = xsrc[t * 256 + tid];
        __syncthreads();

        const float* xf = (const float*)xs_lds;
        floatx4* op = out + (size_t)bh * 3072 + j;

        #pragma unroll 8
        for (int k = 0; k < 64; ++k) {
            float xs = xf[k * 64 + f];             // LDS broadcast
            floatx4 o;
            o.x = fmaf(xs, w.x, bb.x);
            o.y = fmaf(xs, w.y, bb.y);
            o.z = fmaf(xs, w.z, bb.z);
            o.w = fmaf(xs, w.w, bb.w);
            __builtin_nontemporal_store(o, &op[(size_t)k * 3072]);
        }
    }
}

extern "C" void kernel_launch(void* const* d_in, const int* in_sizes, int n_in,
                              void* d_out, int out_size, void* d_ws, size_t ws_size,
                              hipStream_t stream) {
    const float*   x  = (const float*)d_in[0];
    const floatx4* W  = (const floatx4*)d_in[1];
    const floatx4* Bb = (const floatx4*)d_in[2];
    floatx4* out = (floatx4*)d_out;

    ftemb_kernel<<<1536, 256, 0, stream>>>(x, W, Bb, out);
}